// Round 13
// baseline (2076.628 us; speedup 1.0000x reference)
//
#include <hip/hip_runtime.h>
#include <hip/hip_bf16.h>
#include <math.h>
#include <stdint.h>

typedef __attribute__((ext_vector_type(8))) __bf16 bf16x8;
typedef __attribute__((ext_vector_type(4))) float f32x4;
typedef unsigned short us;

#define GLP(p) ((__attribute__((address_space(1))) void*)(p))
#define LDP(p) ((__attribute__((address_space(3))) void*)(p))

static __device__ __forceinline__ float b2f(us u) {
    return __uint_as_float(((unsigned int)u) << 16);
}
static __device__ __forceinline__ us f2b(float f) {
    unsigned int x = __float_as_uint(f);
    return (us)((x + 0x7fffu + ((x >> 16) & 1u)) >> 16);
}

// ---------------- diagnostics: f32 sentinel ----------------
__global__ __launch_bounds__(256) void sentinel(float* out, int n, float v) {
    int i = blockIdx.x * 256 + threadIdx.x;
    if (i < n) out[i] = v;
}

// ---------------- pad zeroing ----------------
__global__ __launch_bounds__(256) void zero_featpad(us* __restrict__ feat) {
    int idx = blockIdx.x * 256 + threadIdx.x;
    if (idx < 40064 * 16) {
        int n = idx >> 4, c = idx & 15;
        feat[(size_t)n * 1216 + 1200 + c] = 0;
    }
}
__global__ __launch_bounds__(256) void zero_x0pad(us* __restrict__ X0) {
    int idx = blockIdx.x * 256 + threadIdx.x;
    if (idx < 4 * 64 * 192) {
        int w = idx / (64 * 192);
        int rem = idx % (64 * 192);
        int rr = rem / 192, c = rem % 192;
        X0[((size_t)w * 40064 + 40000 + rr) * 192 + c] = 0;
    }
}

// ---------------- sort edges by head node ----------------
__global__ __launch_bounds__(256) void count_edges(const int* __restrict__ h, int* __restrict__ counts) {
    int e = blockIdx.x * 256 + threadIdx.x;
    if (e < 400000) atomicAdd(&counts[h[e]], 1);
}

__global__ void scan40k(const int* __restrict__ counts, int* __restrict__ rs) {
    __shared__ int part[1024];
    int tid = threadIdx.x;
    int base = tid * 40;
    int s = 0;
    for (int i = 0; i < 40; ++i) { int idx = base + i; s += (idx < 40000) ? counts[idx] : 0; }
    part[tid] = s;
    __syncthreads();
    for (int off = 1; off < 1024; off <<= 1) {
        int v = (tid >= off) ? part[tid - off] : 0;
        __syncthreads();
        part[tid] += v;
        __syncthreads();
    }
    int run = (tid == 0) ? 0 : part[tid - 1];
    for (int i = 0; i < 40; ++i) {
        int idx = base + i;
        if (idx < 40000) { rs[idx] = run; run += counts[idx]; }
    }
    if (tid == 1023) rs[40000] = part[1023];
}

__global__ __launch_bounds__(256) void scatter_edges(const int* __restrict__ h, const int* __restrict__ rs,
                                                     int* __restrict__ cursor, int* __restrict__ se) {
    int e = blockIdx.x * 256 + threadIdx.x;
    if (e < 400000) {
        int n = h[e];
        int pos = rs[n] + atomicAdd(&cursor[n], 1);
        se[pos] = e;
    }
}

// ---------------- packed bf16 ent ----------------
__global__ __launch_bounds__(256) void pack_ent(const float* __restrict__ ent, us* __restrict__ A0) {
    int idx = blockIdx.x * 256 + threadIdx.x;
    if (idx >= 40064 * 64) return;
    int n = idx >> 6, k = idx & 63;
    A0[idx] = (n < 40000 && k < 50) ? f2b(ent[n * 50 + k]) : (us)0;
}

// ---------------- attention scalar tables ----------------
__global__ __launch_bounds__(256) void build_V0(const float* __restrict__ g0k, const float* __restrict__ attn0,
                                                float* __restrict__ V0) {
    int idx = blockIdx.x * 256 + threadIdx.x;
    if (idx >= 50 * 24) return;
    int k = idx / 24, g = idx % 24;
    int part = g >> 3, hd = g & 7;
    int row = k + (part == 1 ? 100 : (part == 2 ? 50 : 0));
    float s = 0.f;
    for (int u = 0; u < 150; ++u)
        s += g0k[(hd * 150 + row) * 150 + u] * attn0[hd * 150 + u];
    V0[idx] = s;
}

__global__ __launch_bounds__(256) void build_VT0(const float* __restrict__ g0k, const float* __restrict__ attn0,
                                                 us* __restrict__ VT0) {
    int idx = blockIdx.x * 256 + threadIdx.x;
    if (idx >= 128 * 64) return;
    int g = idx >> 6, k = idx & 63;
    us v = 0;
    if (g < 16 && k < 50) {
        int part = g >> 3, hd = g & 7;
        int row = part ? (100 + k) : k;
        float s = 0.f;
        for (int u = 0; u < 150; ++u)
            s += g0k[(hd * 150 + row) * 150 + u] * attn0[hd * 150 + u];
        v = f2b(s);
    }
    VT0[idx] = v;
}

__global__ __launch_bounds__(256) void build_VT1(const float* __restrict__ g1k, const float* __restrict__ attn1,
                                                 us* __restrict__ VT1) {
    int idx = blockIdx.x * 256 + threadIdx.x;
    if (idx >= 128 * 1216) return;
    int g = idx / 1216, k = idx % 1216;
    us v = 0;
    if (g < 16 && k < 1200) {
        int part = g >> 3, hd = g & 7;
        int row = part ? (1350 + k) : k;
        float s = 0.f;
        for (int u = 0; u < 300; ++u)
            s += g1k[((size_t)hd * 2550 + row) * 300 + u] * attn1[hd * 300 + u];
        v = f2b(s);
    }
    VT1[idx] = v;
}

__global__ __launch_bounds__(256) void build_Vr1(const float* __restrict__ g1k, const float* __restrict__ attn1,
                                                 float* __restrict__ Vr1) {
    int idx = blockIdx.x * 256 + threadIdx.x;
    if (idx >= 150 * 8) return;
    int k = idx / 8, hd = idx % 8;
    float s = 0.f;
    for (int u = 0; u < 300; ++u)
        s += g1k[((size_t)hd * 2550 + 1200 + k) * 300 + u] * attn1[hd * 300 + u];
    Vr1[idx] = s;
}

// dwT[j<384][k<64] = dw[k][j]
__global__ __launch_bounds__(256) void build_dwT(const float* __restrict__ dw, us* __restrict__ dwT) {
    int idx = blockIdx.x * 256 + threadIdx.x;
    if (idx >= 384 * 64) return;
    int j = idx >> 6, k = idx & 63;
    us v = 0;
    if (j < 300 && k < 50) v = f2b(dw[k * 300 + j]);
    dwT[idx] = v;
}

// small per-relation projections
__global__ __launch_bounds__(256) void scalar_proj(const void* __restrict__ Av, int aIsF32, int lda, int K,
                                                   const float* __restrict__ V, int ldv, int col0, int G,
                                                   float* __restrict__ out) {
    __shared__ float arow[1216];
    long n = blockIdx.x;
    if (aIsF32) {
        const float* A = (const float*)Av;
        for (int k = threadIdx.x; k < K; k += 256) arow[k] = A[n * lda + k];
    } else {
        const us* A = (const us*)Av;
        for (int k = threadIdx.x; k < K; k += 256) arow[k] = b2f(A[n * lda + k]);
    }
    __syncthreads();
    int g = threadIdx.x >> 4;
    int sl = threadIdx.x & 15;
    if (g < G) {
        float s = 0.f;
        for (int k = sl; k < K; k += 16) s += arow[k] * V[k * ldv + col0 + g];
        for (int off = 8; off; off >>= 1) s += __shfl_down(s, off, 16);
        if (sl == 0) out[n * G + g] = s;
    }
}

// ---------------- softmax per (node, head); pass1 gathers + stores s, pass2 streams s ----------------
__global__ __launch_bounds__(256) void edge_stats2(const int* __restrict__ rs, const int* __restrict__ se,
                                                   const int* __restrict__ rIdx, const int* __restrict__ tIdx,
                                                   const float* __restrict__ sc, const float* __restrict__ arr,
                                                   us* __restrict__ eAT, float* __restrict__ sfac,
                                                   float* __restrict__ sS) {
    int tid = blockIdx.x * 256 + threadIdx.x;
    if (tid >= 40000 * 8) return;
    int n = tid >> 3, hd = tid & 7;
    float ah = sc[n * 16 + hd];
    int p0 = rs[n], p1 = rs[n + 1];
    float m = -INFINITY, d = 0.f;
    for (int p = p0; p < p1; ++p) {
        int e = se[p];
        float s = ah + arr[rIdx[e] * 8 + hd] + sc[tIdx[e] * 16 + 8 + hd];
        s = (s > 0.f) ? s : 0.2f * s;
        sS[(size_t)p * 8 + hd] = s;
        if (s > m) { d = d * expf(m - s) + 1.f; m = s; }
        else d += expf(s - m);
    }
    float inv = 1.f / (d + 1e-10f);
    us* ea = eAT + (size_t)hd * 400000;
    for (int p = p0; p < p1; ++p) {
        float s = sS[(size_t)p * 8 + hd];
        ea[p] = f2b(expf(s - m) * inv);
    }
    sfac[tid] = d * inv;
}

// ---------------- layer-0 raw accumulate: 4 heads/block, LDS-staged metadata ----------------
__global__ __launch_bounds__(256) void agg0x4(int g, const int* __restrict__ rs, const int* __restrict__ se,
                                              const int* __restrict__ rIdx, const int* __restrict__ tIdx,
                                              const us* __restrict__ eAT, const float* __restrict__ sfac,
                                              const float* __restrict__ ent, const float* __restrict__ rel,
                                              us* __restrict__ X0) {
    __shared__ int sr[128], st[128];
    __shared__ float sa[4][128];
    long n = blockIdx.x;
    int tid = threadIdx.x;
    int lane = tid & 63, wave = tid >> 6;
    int hd = 4 * g + wave;
    int k = lane;
    float ev = (k < 50) ? ent[n * 50 + k] : 0.f;
    float xh = sfac[n * 8 + hd] * ev;
    float ra = 0.f, ta = 0.f;
    int p0 = rs[n], p1 = rs[n + 1];
    for (int c0 = p0; c0 < p1; c0 += 128) {
        int cnt = min(128, p1 - c0);
        __syncthreads();
        if (tid < cnt) {
            int e = se[c0 + tid];
            sr[tid] = rIdx[e];
            st[tid] = tIdx[e];
#pragma unroll
            for (int w = 0; w < 4; ++w)
                sa[w][tid] = b2f(eAT[(size_t)(4 * g + w) * 400000 + c0 + tid]);
        }
        __syncthreads();
#pragma unroll 4
        for (int i = 0; i < cnt; ++i) {
            float a = sa[wave][i];
            int r = sr[i], t = st[i];
            if (k < 50) {
                ra += a * rel[r * 50 + k];
                ta += a * ent[(long)t * 50 + k];
            }
        }
    }
    us* row = X0 + ((size_t)wave * 40064 + n) * 192;
    if (k < 50) { row[k] = f2b(xh); row[50 + k] = f2b(ra); row[100 + k] = f2b(ta); }
    if (lane < 42) row[150 + lane] = 0;
}

// ---------------- B builders ----------------
__global__ __launch_bounds__(256) void build_B0T8(const float* __restrict__ g0k, us* __restrict__ B) {
    int idx = blockIdx.x * 256 + threadIdx.x;
    if (idx >= 8 * 256 * 192) return;
    int hd = idx / (256 * 192);
    int u = (idx / 192) % 256, k = idx % 192;
    us v = 0;
    if (u < 150 && k < 150) v = f2b(g0k[((size_t)hd * 150 + k) * 150 + u]);
    B[idx] = v;
}

// B1Th2 via LDS tile transpose: coalesced g1k reads (u-fast) + coalesced B writes (k-fast)
__global__ __launch_bounds__(256) void build_B1Th2T(int g, const float* __restrict__ g1k, us* __restrict__ B) {
    __shared__ us tile[64][65];
    int j0 = blockIdx.x * 64, k0 = blockIdx.y * 64;
    int tl = threadIdx.x & 63, th = threadIdx.x >> 6;
#pragma unroll 4
    for (int i = 0; i < 16; ++i) {
        int jj = j0 + tl;
        int kk = k0 + th + 4 * i;
        us v = 0;
        if (jj < 1216 && kk < 1200) {
            int blk = jj / 304, u = jj % 304;
            if (u < 300) {
                int hd = 2 * g + (blk & 1);
                int row = (blk >= 2) ? (1350 + kk) : kk;
                v = f2b(g1k[((size_t)hd * 2550 + row) * 300 + u]);
            }
        }
        tile[tl][th + 4 * i] = v;
    }
    __syncthreads();
#pragma unroll 4
    for (int i = 0; i < 16; ++i) {
        int k = k0 + tl;
        int j = j0 + th + 4 * i;
        if (j < 1280 && k < 1216) B[(size_t)j * 1216 + k] = tile[th + 4 * i][tl];
    }
}

// ============ MFMA GEMM core: single-buffer 32KB (5 blocks/CU TLP) + T2 swizzle + T1 + T5 ============
#define GEMM_BODY(EPILOG)                                                                       \
    __shared__ __align__(16) us As[128 * 64];                                                   \
    __shared__ __align__(16) us Bs[128 * 64];                                                   \
    const int tid = threadIdx.x;                                                                \
    const int lane = tid & 63, wave = tid >> 6;                                                 \
    const int wr = wave >> 1, wc = wave & 1;                                                    \
    const int r16 = lane & 15, g4 = lane >> 4;                                                  \
    const int gx = gridDim.x;                                                                   \
    const int nwg = gx * gridDim.y;                                                             \
    const int orig = blockIdx.y * gx + blockIdx.x;                                              \
    const int q8 = nwg >> 3, r8 = nwg & 7;                                                      \
    const int xcd = orig & 7;                                                                   \
    const int lg = (xcd < r8 ? xcd * (q8 + 1) : r8 * (q8 + 1) + (xcd - r8) * q8) + (orig >> 3); \
    const long bm = lg / gx, bn = lg % gx;                                                      \
    f32x4 acc[4][4];                                                                            \
    _Pragma("unroll") for (int m = 0; m < 4; ++m)                                               \
        _Pragma("unroll") for (int n = 0; n < 4; ++n) acc[m][n] = (f32x4){0.f, 0.f, 0.f, 0.f};  \
    const int nt = K >> 6;                                                                      \
    const int sxor = (r16 & 7) << 3;                                                            \
    for (int t = 0; t < nt; ++t) {                                                              \
        int kt = t << 6;                                                                        \
        _Pragma("unroll") for (int i = 0; i < 4; ++i) {                                         \
            int idx = tid + i * 256;                                                            \
            int row = idx >> 3, sub = idx & 7;                                                  \
            int scol = ((sub ^ (row & 7)) << 3);                                                \
            const us* ga = A + (bm * 128 + row) * (long)K + kt + scol;                          \
            __builtin_amdgcn_global_load_lds(GLP(ga), LDP(&As[idx * 8]), 16, 0, 0);             \
        }                                                                                       \
        _Pragma("unroll") for (int i = 0; i < 4; ++i) {                                         \
            int idx = tid + i * 256;                                                            \
            int row = idx >> 3, sub = idx & 7;                                                  \
            int scol = ((sub ^ (row & 7)) << 3);                                                \
            const us* gb = BT + (bn * 128 + row) * (long)K + kt + scol;                         \
            __builtin_amdgcn_global_load_lds(GLP(gb), LDP(&Bs[idx * 8]), 16, 0, 0);             \
        }                                                                                       \
        asm volatile("s_waitcnt vmcnt(0)" ::: "memory");                                        \
        __syncthreads();                                                                        \
        __builtin_amdgcn_s_setprio(1);                                                          \
        _Pragma("unroll") for (int kk = 0; kk < 2; ++kk) {                                      \
            bf16x8 af[4], bfr[4];                                                               \
            _Pragma("unroll") for (int m = 0; m < 4; ++m)                                       \
                af[m] = *(const bf16x8*)&As[(wr * 64 + m * 16 + r16) * 64 +                     \
                                            ((kk * 32 + g4 * 8) ^ sxor)];                       \
            _Pragma("unroll") for (int n = 0; n < 4; ++n)                                       \
                bfr[n] = *(const bf16x8*)&Bs[(wc * 64 + n * 16 + r16) * 64 +                    \
                                             ((kk * 32 + g4 * 8) ^ sxor)];                      \
            _Pragma("unroll") for (int m = 0; m < 4; ++m)                                       \
                _Pragma("unroll") for (int n = 0; n < 4; ++n)                                   \
                    acc[m][n] = __builtin_amdgcn_mfma_f32_16x16x32_bf16(af[m], bfr[n],          \
                                                                        acc[m][n], 0, 0, 0);    \
        }                                                                                       \
        __builtin_amdgcn_s_setprio(0);                                                          \
        __syncthreads();                                                                        \
    }                                                                                           \
    _Pragma("unroll") for (int m = 0; m < 4; ++m)                                               \
        _Pragma("unroll") for (int n = 0; n < 4; ++n)                                           \
            _Pragma("unroll") for (int j = 0; j < 4; ++j) { EPILOG }

// bf16-out variant (z-sliced)
__global__ __launch_bounds__(256) void gemm_bt(const us* __restrict__ A_, const us* __restrict__ BT_,
                                               us* __restrict__ C, int K, int ldc, int nColReal,
                                               int colOff0, int colOffZ, long aStrideZ, long btStrideZ,
                                               int act) {
    const int z = blockIdx.z;
    const us* A = A_ + (size_t)z * aStrideZ;
    const us* BT = BT_ + (size_t)z * btStrideZ;
    const int colBase = colOff0 + z * colOffZ;
    GEMM_BODY(
        int cc = (int)bn * 128 + wc * 64 + n * 16 + r16;
        if (cc < nColReal) {
            long row = bm * 128 + wr * 64 + m * 16 + g4 * 4 + j;
            float v = acc[m][n][j];
            if (act) v = (v > 0.f) ? v : expm1f(v);
            C[row * (long)ldc + colBase + cc] = f2b(v);
        })
}

// f32-out variant (attention scalars sc; optional bias for dense out-init)
__global__ __launch_bounds__(256) void gemm_bt_f32(const us* __restrict__ A, const us* __restrict__ BT,
                                                   float* __restrict__ C, int K, int ldc, int nColReal,
                                                   const float* __restrict__ bias) {
    GEMM_BODY(
        int cc = (int)bn * 128 + wc * 64 + n * 16 + r16;
        if (cc < nColReal) {
            long row = bm * 128 + wr * 64 + m * 16 + g4 * 4 + j;
            float v = acc[m][n][j];
            if (bias) v += bias[cc];
            C[row * (long)ldc + cc] = v;
        })
}

// ---------------- small relation matmuls ----------------
__global__ __launch_bounds__(256) void rel0_kernel(const float* __restrict__ rel, const float* __restrict__ g0rk,
                                                   float* __restrict__ rel0b) {
    int idx = blockIdx.x * 256 + threadIdx.x;
    if (idx >= 500 * 150) return;
    int rI = idx / 150, u = idx % 150;
    float s = 0.f;
    for (int k = 0; k < 50; ++k) s += rel[rI * 50 + k] * g0rk[k * 150 + u];
    rel0b[idx] = s;
}

__global__ __launch_bounds__(256) void pr1_kernel(const float* __restrict__ rel0b, const float* __restrict__ g1k,
                                                  us* __restrict__ PR1b) {
    int idx = blockIdx.x * 256 + threadIdx.x;
    if (idx >= 500 * 2400) return;
    int rI = idx / 2400, jj = idx % 2400;
    int hd = jj / 300, u = jj % 300;
    float s = 0.f;
    for (int k = 0; k < 150; ++k)
        s += rel0b[rI * 150 + k] * g1k[((size_t)hd * 2550 + 1200 + k) * 300 + u];
    PR1b[idx] = f2b(s);
}

__global__ __launch_bounds__(256) void rel1_kernel(const float* __restrict__ rel0b, const float* __restrict__ g1rk,
                                                   float* __restrict__ out) {
    int idx = blockIdx.x * 256 + threadIdx.x;
    if (idx >= 500 * 300) return;
    int rI = idx / 300, u = idx % 300;
    float s = 0.f;
    for (int k = 0; k < 150; ++k) s += rel0b[rI * 150 + k] * g1rk[k * 300 + u];
    out[idx] = s;
}

// ---------------- layer-1 aggregation: 2 heads per launch, LDS-staged, race-free ----------------
__global__ __launch_bounds__(256) void agg1h2(int g, const int* __restrict__ rs, const int* __restrict__ se,
                                              const int* __restrict__ rIdx, const int* __restrict__ tIdx,
                                              const us* __restrict__ eAT, const float* __restrict__ sfac,
                                              const us* __restrict__ C1g2, const us* __restrict__ PR1b,
                                              float* __restrict__ outf) {
    __shared__ int sr[128], st[128];
    __shared__ float sa0[128], sa1[128];
    long n = blockIdx.x;
    int tid = threadIdx.x;
    int hd0 = 2 * g, hd1 = hd0 + 1;
    int d = tid, d2 = tid + 256;
    bool a2 = (d2 < 300);
    float sf0 = sfac[n * 8 + hd0], sf1 = sfac[n * 8 + hd1];
    const us* crow = C1g2 + (size_t)n * 1216;
    float acc00 = sf0 * b2f(crow[d]);
    float acc10 = sf1 * b2f(crow[304 + d]);
    float acc01 = a2 ? sf0 * b2f(crow[d2]) : 0.f;
    float acc11 = a2 ? sf1 * b2f(crow[304 + d2]) : 0.f;
    const us* ea0 = eAT + (size_t)hd0 * 400000;
    const us* ea1 = eAT + (size_t)hd1 * 400000;
    int p0 = rs[n], p1 = rs[n + 1];
    for (int c0 = p0; c0 < p1; c0 += 128) {
        int cnt = min(128, p1 - c0);
        __syncthreads();
        if (tid < cnt) {
            int e = se[c0 + tid];
            sr[tid] = rIdx[e];
            st[tid] = tIdx[e];
            sa0[tid] = b2f(ea0[c0 + tid]);
            sa1[tid] = b2f(ea1[c0 + tid]);
        }
        __syncthreads();
#pragma unroll 4
        for (int i = 0; i < cnt; ++i) {
            int r = sr[i], t = st[i];
            float a0 = sa0[i], a1 = sa1[i];
            const us* ct = C1g2 + (size_t)t * 1216;
            const us* pr = PR1b + (size_t)r * 2400;
            acc00 += a0 * (b2f(pr[hd0 * 300 + d]) + b2f(ct[608 + d]));
            acc10 += a1 * (b2f(pr[hd1 * 300 + d]) + b2f(ct[912 + d]));
            if (a2) {
                acc01 += a0 * (b2f(pr[hd0 * 300 + d2]) + b2f(ct[608 + d2]));
                acc11 += a1 * (b2f(pr[hd1 * 300 + d2]) + b2f(ct[912 + d2]));
            }
        }
    }
    float v00 = (acc00 > 0.f) ? acc00 : expm1f(acc00);
    float v10 = (acc10 > 0.f) ? acc10 : expm1f(acc10);
    outf[n * 300 + d] += v00 + v10;
    if (a2) {
        float v01 = (acc01 > 0.f) ? acc01 : expm1f(acc01);
        float v11 = (acc11 > 0.f) ? acc11 : expm1f(acc11);
        outf[n * 300 + d2] += v01 + v11;
    }
}

extern "C" void kernel_launch(void* const* d_in, const int* in_sizes, int n_in,
                              void* d_out, int out_size, void* d_ws, size_t ws_size,
                              hipStream_t stream) {
    const int* hIdx = (const int*)d_in[0];
    const int* rIdx = (const int*)d_in[1];
    const int* tIdx = (const int*)d_in[2];
    const float* ent  = (const float*)d_in[3];
    const float* rel  = (const float*)d_in[4];
    const float* g0k  = (const float*)d_in[5];
    const float* at0w = (const float*)d_in[6];
    const float* g0rk = (const float*)d_in[7];
    const float* g1k  = (const float*)d_in[8];
    const float* at1w = (const float*)d_in[9];
    const float* g1rk = (const float*)d_in[10];
    const float* dw   = (const float*)d_in[11];
    const float* db   = (const float*)d_in[12];
    float* outf = (float*)d_out;

    {
        const int exp_sz[13] = {400000, 400000, 400000, 2000000, 25000, 180000, 1200,
                                7500, 6120000, 2400, 45000, 15000, 300};
        bool ok = (n_in == 13);
        for (int i = 0; ok && i < 13; ++i) ok = (in_sizes[i] == exp_sz[i]);
        if (!ok) {
            sentinel<<<(out_size + 255) / 256, 256, 0, stream>>>(outf, out_size, 44.0f);
            return;
        }
    }

    char* p = (char*)d_ws;
    auto carve = [&](size_t bytes) -> char* {
        char* r = p;
        p += (bytes + 255) & ~(size_t)255;
        return r;
    };
    int* counts = (int*)carve(40000 * 4);
    int* cursor = (int*)carve(40000 * 4);
    int* rs     = (int*)carve(40001 * 4);
    int* se     = (int*)carve(400000 * 4);
    float* sc   = (float*)carve((size_t)40064 * 16 * 4);
    float* arS  = (float*)carve(500 * 8 * 4);
    us* eAT     = (us*)carve((size_t)8 * 400000 * 2);
    float* sfac = (float*)carve((size_t)40000 * 8 * 4);
    float* V0  = (float*)carve(50 * 24 * 4);
    float* Vr1 = (float*)carve(150 * 8 * 4);
    float* rel0b = (float*)carve(500 * 150 * 4);
    us* PR1b  = (us*)carve((size_t)500 * 2400 * 2);
    us* VT0   = (us*)carve((size_t)128 * 64 * 2);
    us* VT1   = (us*)carve((size_t)128 * 1216 * 2);
    us* dwT   = (us*)carve((size_t)384 * 64 * 2);
    us* B0T8  = (us*)carve((size_t)8 * 256 * 192 * 2);
    us* B1Th2 = (us*)carve((size_t)1280 * 1216 * 2);
    us* feat  = (us*)carve((size_t)40064 * 1216 * 2);
    // tail: A0 -> sS(edge_stats scratch) -> X0 -> sS -> C1g2 (sequentially dead)
    char* tail = p;
    us* A0    = (us*)tail;
    float* sS = (float*)tail;
    us* X0    = (us*)tail;
    us* C1g2  = (us*)tail;
    size_t tailNeed = (size_t)40064 * 1216 * 2;
    size_t totalNeed = (size_t)(tail - (char*)d_ws) + tailNeed;
    if (totalNeed > ws_size) {
        sentinel<<<(out_size + 255) / 256, 256, 0, stream>>>(outf, out_size, 42.0f);
        return;
    }

    hipMemsetAsync(counts, 0, 40000 * 4, stream);
    hipMemsetAsync(cursor, 0, 40000 * 4, stream);
    zero_featpad<<<(40064 * 16 + 255) / 256, 256, 0, stream>>>(feat);

    count_edges<<<1563, 256, 0, stream>>>(hIdx, counts);
    scan40k<<<1, 1024, 0, stream>>>(counts, rs);
    scatter_edges<<<1563, 256, 0, stream>>>(hIdx, rs, cursor, se);

    // ---- layer 0: attention scalars + dense out-init via MFMA (A0 alive in tail) ----
    pack_ent<<<(40064 * 64 + 255) / 256, 256, 0, stream>>>(ent, A0);
    build_VT0<<<(128 * 64 + 255) / 256, 256, 0, stream>>>(g0k, at0w, VT0);
    gemm_bt_f32<<<dim3(1, 313), 256, 0, stream>>>(A0, VT0, sc, 64, 16, 16, nullptr);
    build_dwT<<<(384 * 64 + 255) / 256, 256, 0, stream>>>(dw, dwT);
    gemm_bt_f32<<<dim3(3, 313), 256, 0, stream>>>(A0, dwT, outf, 64, 300, 300, db);
    build_V0<<<5, 256, 0, stream>>>(g0k, at0w, V0);
    scalar_proj<<<500, 256, 0, stream>>>(rel, 1, 50, 50, V0, 24, 16, 8, arS);
    edge_stats2<<<1250, 256, 0, stream>>>(rs, se, rIdx, tIdx, sc, arS, eAT, sfac, sS);  // A0 dead now

    zero_x0pad<<<(4 * 64 * 192 + 255) / 256, 256, 0, stream>>>(X0);  // after sS dead
    build_B0T8<<<(8 * 256 * 192 + 255) / 256, 256, 0, stream>>>(g0k, B0T8);
    for (int g = 0; g < 2; ++g) {
        agg0x4<<<40000, 256, 0, stream>>>(g, rs, se, rIdx, tIdx, eAT, sfac, ent, rel, X0);
        gemm_bt<<<dim3(2, 313, 4), 256, 0, stream>>>(X0, B0T8 + (size_t)g * 4 * 256 * 192, feat,
                                                     192, 1216, 150, g * 600, 150,
                                                     (long)40064 * 192, (long)256 * 192, 1);
    }

    // ---- layer 1 prep ----
    rel0_kernel<<<(500 * 150 + 255) / 256, 256, 0, stream>>>(rel, g0rk, rel0b);
    build_VT1<<<(128 * 1216 + 255) / 256, 256, 0, stream>>>(g1k, at1w, VT1);
    build_Vr1<<<5, 256, 0, stream>>>(g1k, at1w, Vr1);
    gemm_bt_f32<<<dim3(1, 313), 256, 0, stream>>>(feat, VT1, sc, 1216, 16, 16, nullptr);
    scalar_proj<<<500, 256, 0, stream>>>(rel0b, 1, 150, 150, Vr1, 8, 0, 8, arS);
    edge_stats2<<<1250, 256, 0, stream>>>(rs, se, rIdx, tIdx, sc, arS, eAT, sfac, sS);  // X0 dead now
    pr1_kernel<<<(500 * 2400 + 255) / 256, 256, 0, stream>>>(rel0b, g1k, PR1b);

    // ---- layer 1: head pairs ----
    for (int g = 0; g < 4; ++g) {
        build_B1Th2T<<<dim3(20, 19), 256, 0, stream>>>(g, g1k, B1Th2);
        gemm_bt<<<dim3(10, 313, 1), 256, 0, stream>>>(feat, B1Th2, C1g2,
                                                      1216, 1216, 1216, 0, 0, 0, 0, 0);
        agg1h2<<<40000, 256, 0, stream>>>(g, rs, se, rIdx, tIdx, eAT, sfac, C1g2, PR1b, outf);
    }

    rel1_kernel<<<(500 * 300 + 255) / 256, 256, 0, stream>>>(rel0b, g1rk, outf + (size_t)40000 * 300);
}

// Round 14
// 1938.502 us; speedup vs baseline: 1.0713x; 1.0713x over previous
//
#include <hip/hip_runtime.h>
#include <hip/hip_bf16.h>
#include <math.h>
#include <stdint.h>

typedef __attribute__((ext_vector_type(8))) __bf16 bf16x8;
typedef __attribute__((ext_vector_type(4))) float f32x4;
typedef unsigned short us;

#define GLP(p) ((__attribute__((address_space(1))) void*)(p))
#define LDP(p) ((__attribute__((address_space(3))) void*)(p))

static __device__ __forceinline__ float b2f(us u) {
    return __uint_as_float(((unsigned int)u) << 16);
}
static __device__ __forceinline__ us f2b(float f) {
    unsigned int x = __float_as_uint(f);
    return (us)((x + 0x7fffu + ((x >> 16) & 1u)) >> 16);
}

// ---------------- diagnostics: f32 sentinel ----------------
__global__ __launch_bounds__(256) void sentinel(float* out, int n, float v) {
    int i = blockIdx.x * 256 + threadIdx.x;
    if (i < n) out[i] = v;
}

// ---------------- pad zeroing ----------------
__global__ __launch_bounds__(256) void zero_featpad(us* __restrict__ feat) {
    int idx = blockIdx.x * 256 + threadIdx.x;
    if (idx < 40064 * 16) {
        int n = idx >> 4, c = idx & 15;
        feat[(size_t)n * 1216 + 1200 + c] = 0;
    }
}
__global__ __launch_bounds__(256) void zero_x0pad(us* __restrict__ X0) {
    int idx = blockIdx.x * 256 + threadIdx.x;
    if (idx < 4 * 64 * 192) {
        int w = idx / (64 * 192);
        int rem = idx % (64 * 192);
        int rr = rem / 192, c = rem % 192;
        X0[((size_t)w * 40064 + 40000 + rr) * 192 + c] = 0;
    }
}

// ---------------- sort edges by head node ----------------
__global__ __launch_bounds__(256) void count_edges(const int* __restrict__ h, int* __restrict__ counts) {
    int e = blockIdx.x * 256 + threadIdx.x;
    if (e < 400000) atomicAdd(&counts[h[e]], 1);
}

__global__ void scan40k(const int* __restrict__ counts, int* __restrict__ rs) {
    __shared__ int part[1024];
    int tid = threadIdx.x;
    int base = tid * 40;
    int s = 0;
    for (int i = 0; i < 40; ++i) { int idx = base + i; s += (idx < 40000) ? counts[idx] : 0; }
    part[tid] = s;
    __syncthreads();
    for (int off = 1; off < 1024; off <<= 1) {
        int v = (tid >= off) ? part[tid - off] : 0;
        __syncthreads();
        part[tid] += v;
        __syncthreads();
    }
    int run = (tid == 0) ? 0 : part[tid - 1];
    for (int i = 0; i < 40; ++i) {
        int idx = base + i;
        if (idx < 40000) { rs[idx] = run; run += counts[idx]; }
    }
    if (tid == 1023) rs[40000] = part[1023];
}

__global__ __launch_bounds__(256) void scatter_edges(const int* __restrict__ h, const int* __restrict__ rs,
                                                     int* __restrict__ cursor, int* __restrict__ se) {
    int e = blockIdx.x * 256 + threadIdx.x;
    if (e < 400000) {
        int n = h[e];
        int pos = rs[n] + atomicAdd(&cursor[n], 1);
        se[pos] = e;
    }
}

// ---------------- packed bf16 ent ----------------
__global__ __launch_bounds__(256) void pack_ent(const float* __restrict__ ent, us* __restrict__ A0) {
    int idx = blockIdx.x * 256 + threadIdx.x;
    if (idx >= 40064 * 64) return;
    int n = idx >> 6, k = idx & 63;
    A0[idx] = (n < 40000 && k < 50) ? f2b(ent[n * 50 + k]) : (us)0;
}

// ---------------- attention scalar tables ----------------
__global__ __launch_bounds__(256) void build_V0(const float* __restrict__ g0k, const float* __restrict__ attn0,
                                                float* __restrict__ V0) {
    int idx = blockIdx.x * 256 + threadIdx.x;
    if (idx >= 50 * 24) return;
    int k = idx / 24, g = idx % 24;
    int part = g >> 3, hd = g & 7;
    int row = k + (part == 1 ? 100 : (part == 2 ? 50 : 0));
    float s = 0.f;
    for (int u = 0; u < 150; ++u)
        s += g0k[(hd * 150 + row) * 150 + u] * attn0[hd * 150 + u];
    V0[idx] = s;
}

__global__ __launch_bounds__(256) void build_VT0(const float* __restrict__ g0k, const float* __restrict__ attn0,
                                                 us* __restrict__ VT0) {
    int idx = blockIdx.x * 256 + threadIdx.x;
    if (idx >= 128 * 64) return;
    int g = idx >> 6, k = idx & 63;
    us v = 0;
    if (g < 16 && k < 50) {
        int part = g >> 3, hd = g & 7;
        int row = part ? (100 + k) : k;
        float s = 0.f;
        for (int u = 0; u < 150; ++u)
            s += g0k[(hd * 150 + row) * 150 + u] * attn0[hd * 150 + u];
        v = f2b(s);
    }
    VT0[idx] = v;
}

__global__ __launch_bounds__(256) void build_VT1(const float* __restrict__ g1k, const float* __restrict__ attn1,
                                                 us* __restrict__ VT1) {
    int idx = blockIdx.x * 256 + threadIdx.x;
    if (idx >= 128 * 1216) return;
    int g = idx / 1216, k = idx % 1216;
    us v = 0;
    if (g < 16 && k < 1200) {
        int part = g >> 3, hd = g & 7;
        int row = part ? (1350 + k) : k;
        float s = 0.f;
        for (int u = 0; u < 300; ++u)
            s += g1k[((size_t)hd * 2550 + row) * 300 + u] * attn1[hd * 300 + u];
        v = f2b(s);
    }
    VT1[idx] = v;
}

__global__ __launch_bounds__(256) void build_Vr1(const float* __restrict__ g1k, const float* __restrict__ attn1,
                                                 float* __restrict__ Vr1) {
    int idx = blockIdx.x * 256 + threadIdx.x;
    if (idx >= 150 * 8) return;
    int k = idx / 8, hd = idx % 8;
    float s = 0.f;
    for (int u = 0; u < 300; ++u)
        s += g1k[((size_t)hd * 2550 + 1200 + k) * 300 + u] * attn1[hd * 300 + u];
    Vr1[idx] = s;
}

// dwT[j<384][k<64] = dw[k][j]
__global__ __launch_bounds__(256) void build_dwT(const float* __restrict__ dw, us* __restrict__ dwT) {
    int idx = blockIdx.x * 256 + threadIdx.x;
    if (idx >= 384 * 64) return;
    int j = idx >> 6, k = idx & 63;
    us v = 0;
    if (j < 300 && k < 50) v = f2b(dw[k * 300 + j]);
    dwT[idx] = v;
}

// small per-relation projections
__global__ __launch_bounds__(256) void scalar_proj(const void* __restrict__ Av, int aIsF32, int lda, int K,
                                                   const float* __restrict__ V, int ldv, int col0, int G,
                                                   float* __restrict__ out) {
    __shared__ float arow[1216];
    long n = blockIdx.x;
    if (aIsF32) {
        const float* A = (const float*)Av;
        for (int k = threadIdx.x; k < K; k += 256) arow[k] = A[n * lda + k];
    } else {
        const us* A = (const us*)Av;
        for (int k = threadIdx.x; k < K; k += 256) arow[k] = b2f(A[n * lda + k]);
    }
    __syncthreads();
    int g = threadIdx.x >> 4;
    int sl = threadIdx.x & 15;
    if (g < G) {
        float s = 0.f;
        for (int k = sl; k < K; k += 16) s += arow[k] * V[k * ldv + col0 + g];
        for (int off = 8; off; off >>= 1) s += __shfl_down(s, off, 16);
        if (sl == 0) out[n * G + g] = s;
    }
}

// ---------------- softmax per (node, head); pass1 gathers + stores s, pass2 streams s ----------------
__global__ __launch_bounds__(256) void edge_stats2(const int* __restrict__ rs, const int* __restrict__ se,
                                                   const int* __restrict__ rIdx, const int* __restrict__ tIdx,
                                                   const float* __restrict__ sc, const float* __restrict__ arr,
                                                   us* __restrict__ eAT, float* __restrict__ sfac,
                                                   float* __restrict__ sS) {
    int tid = blockIdx.x * 256 + threadIdx.x;
    if (tid >= 40000 * 8) return;
    int n = tid >> 3, hd = tid & 7;
    float ah = sc[n * 16 + hd];
    int p0 = rs[n], p1 = rs[n + 1];
    float m = -INFINITY, d = 0.f;
    for (int p = p0; p < p1; ++p) {
        int e = se[p];
        float s = ah + arr[rIdx[e] * 8 + hd] + sc[tIdx[e] * 16 + 8 + hd];
        s = (s > 0.f) ? s : 0.2f * s;
        sS[(size_t)p * 8 + hd] = s;
        if (s > m) { d = d * expf(m - s) + 1.f; m = s; }
        else d += expf(s - m);
    }
    float inv = 1.f / (d + 1e-10f);
    us* ea = eAT + (size_t)hd * 400000;
    for (int p = p0; p < p1; ++p) {
        float s = sS[(size_t)p * 8 + hd];
        ea[p] = f2b(expf(s - m) * inv);
    }
    sfac[tid] = d * inv;
}

// ---------------- layer-0 raw accumulate: 4 heads/block, LDS-staged metadata ----------------
__global__ __launch_bounds__(256) void agg0x4(int g, const int* __restrict__ rs, const int* __restrict__ se,
                                              const int* __restrict__ rIdx, const int* __restrict__ tIdx,
                                              const us* __restrict__ eAT, const float* __restrict__ sfac,
                                              const float* __restrict__ ent, const float* __restrict__ rel,
                                              us* __restrict__ X0) {
    __shared__ int sr[128], st[128];
    __shared__ float sa[4][128];
    long n = blockIdx.x;
    int tid = threadIdx.x;
    int lane = tid & 63, wave = tid >> 6;
    int hd = 4 * g + wave;
    int k = lane;
    float ev = (k < 50) ? ent[n * 50 + k] : 0.f;
    float xh = sfac[n * 8 + hd] * ev;
    float ra = 0.f, ta = 0.f;
    int p0 = rs[n], p1 = rs[n + 1];
    for (int c0 = p0; c0 < p1; c0 += 128) {
        int cnt = min(128, p1 - c0);
        __syncthreads();
        if (tid < cnt) {
            int e = se[c0 + tid];
            sr[tid] = rIdx[e];
            st[tid] = tIdx[e];
#pragma unroll
            for (int w = 0; w < 4; ++w)
                sa[w][tid] = b2f(eAT[(size_t)(4 * g + w) * 400000 + c0 + tid]);
        }
        __syncthreads();
#pragma unroll 4
        for (int i = 0; i < cnt; ++i) {
            float a = sa[wave][i];
            int r = sr[i], t = st[i];
            if (k < 50) {
                ra += a * rel[r * 50 + k];
                ta += a * ent[(long)t * 50 + k];
            }
        }
    }
    us* row = X0 + ((size_t)wave * 40064 + n) * 192;
    if (k < 50) { row[k] = f2b(xh); row[50 + k] = f2b(ra); row[100 + k] = f2b(ta); }
    if (lane < 42) row[150 + lane] = 0;
}

// ---------------- B builders ----------------
__global__ __launch_bounds__(256) void build_B0T8(const float* __restrict__ g0k, us* __restrict__ B) {
    int idx = blockIdx.x * 256 + threadIdx.x;
    if (idx >= 8 * 256 * 192) return;
    int hd = idx / (256 * 192);
    int u = (idx / 192) % 256, k = idx % 192;
    us v = 0;
    if (u < 150 && k < 150) v = f2b(g0k[((size_t)hd * 150 + k) * 150 + u]);
    B[idx] = v;
}

// B1Th2 via LDS tile transpose: coalesced g1k reads + coalesced B writes
__global__ __launch_bounds__(256) void build_B1Th2T(int g, const float* __restrict__ g1k, us* __restrict__ B) {
    __shared__ us tile[64][65];
    int j0 = blockIdx.x * 64, k0 = blockIdx.y * 64;
    int tl = threadIdx.x & 63, th = threadIdx.x >> 6;
#pragma unroll 4
    for (int i = 0; i < 16; ++i) {
        int jj = j0 + tl;
        int kk = k0 + th + 4 * i;
        us v = 0;
        if (jj < 1216 && kk < 1200) {
            int blk = jj / 304, u = jj % 304;
            if (u < 300) {
                int hd = 2 * g + (blk & 1);
                int row = (blk >= 2) ? (1350 + kk) : kk;
                v = f2b(g1k[((size_t)hd * 2550 + row) * 300 + u]);
            }
        }
        tile[tl][th + 4 * i] = v;
    }
    __syncthreads();
#pragma unroll 4
    for (int i = 0; i < 16; ++i) {
        int k = k0 + tl;
        int j = j0 + th + 4 * i;
        if (j < 1280 && k < 1216) B[(size_t)j * 1216 + k] = tile[th + 4 * i][tl];
    }
}

// ============ MFMA GEMM core (round-12 measured-best): T2 swizzle + dbuf + vmcnt(8) + T1 + T5 ============
#define GEMM_BODY(EPILOG)                                                                       \
    __shared__ __align__(16) us As[2][128 * 64];                                                \
    __shared__ __align__(16) us Bs[2][128 * 64];                                                \
    const int tid = threadIdx.x;                                                                \
    const int lane = tid & 63, wave = tid >> 6;                                                 \
    const int wr = wave >> 1, wc = wave & 1;                                                    \
    const int r16 = lane & 15, g4 = lane >> 4;                                                  \
    const int gx = gridDim.x;                                                                   \
    const int nwg = gx * gridDim.y;                                                             \
    const int orig = blockIdx.y * gx + blockIdx.x;                                              \
    const int q8 = nwg >> 3, r8 = nwg & 7;                                                      \
    const int xcd = orig & 7;                                                                   \
    const int lg = (xcd < r8 ? xcd * (q8 + 1) : r8 * (q8 + 1) + (xcd - r8) * q8) + (orig >> 3); \
    const long bm = lg / gx, bn = lg % gx;                                                      \
    f32x4 acc[4][4];                                                                            \
    _Pragma("unroll") for (int m = 0; m < 4; ++m)                                               \
        _Pragma("unroll") for (int n = 0; n < 4; ++n) acc[m][n] = (f32x4){0.f, 0.f, 0.f, 0.f};  \
    auto stage = [&](int buf, int kt) {                                                         \
        _Pragma("unroll") for (int i = 0; i < 4; ++i) {                                         \
            int idx = tid + i * 256;                                                            \
            int row = idx >> 3, sub = idx & 7;                                                  \
            int scol = ((sub ^ (row & 7)) << 3);                                                \
            const us* ga = A + (bm * 128 + row) * (long)K + kt + scol;                          \
            __builtin_amdgcn_global_load_lds(GLP(ga), LDP(&As[buf][idx * 8]), 16, 0, 0);        \
        }                                                                                       \
        _Pragma("unroll") for (int i = 0; i < 4; ++i) {                                         \
            int idx = tid + i * 256;                                                            \
            int row = idx >> 3, sub = idx & 7;                                                  \
            int scol = ((sub ^ (row & 7)) << 3);                                                \
            const us* gb = BT + (bn * 128 + row) * (long)K + kt + scol;                         \
            __builtin_amdgcn_global_load_lds(GLP(gb), LDP(&Bs[buf][idx * 8]), 16, 0, 0);        \
        }                                                                                       \
    };                                                                                          \
    const int nt = K >> 6;                                                                      \
    stage(0, 0);                                                                                \
    const int sxor = (r16 & 7) << 3;                                                            \
    for (int t = 0; t < nt; ++t) {                                                              \
        int cur = t & 1;                                                                        \
        if (t + 1 < nt) {                                                                       \
            stage(cur ^ 1, (t + 1) << 6);                                                       \
            asm volatile("s_waitcnt vmcnt(8)" ::: "memory");                                    \
        } else {                                                                                \
            asm volatile("s_waitcnt vmcnt(0)" ::: "memory");                                    \
        }                                                                                       \
        __builtin_amdgcn_s_barrier();                                                           \
        asm volatile("" ::: "memory");                                                          \
        __builtin_amdgcn_s_setprio(1);                                                          \
        _Pragma("unroll") for (int kk = 0; kk < 2; ++kk) {                                      \
            bf16x8 af[4], bfr[4];                                                               \
            _Pragma("unroll") for (int m = 0; m < 4; ++m)                                       \
                af[m] = *(const bf16x8*)&As[cur][(wr * 64 + m * 16 + r16) * 64 +                \
                                               ((kk * 32 + g4 * 8) ^ sxor)];                    \
            _Pragma("unroll") for (int n = 0; n < 4; ++n)                                       \
                bfr[n] = *(const bf16x8*)&Bs[cur][(wc * 64 + n * 16 + r16) * 64 +               \
                                                ((kk * 32 + g4 * 8) ^ sxor)];                   \
            _Pragma("unroll") for (int m = 0; m < 4; ++m)                                       \
                _Pragma("unroll") for (int n = 0; n < 4; ++n)                                   \
                    acc[m][n] = __builtin_amdgcn_mfma_f32_16x16x32_bf16(af[m], bfr[n],          \
                                                                        acc[m][n], 0, 0, 0);    \
        }                                                                                       \
        __builtin_amdgcn_s_setprio(0);                                                          \
        asm volatile("" ::: "memory");                                                          \
        __builtin_amdgcn_s_barrier();                                                           \
    }                                                                                           \
    _Pragma("unroll") for (int m = 0; m < 4; ++m)                                               \
        _Pragma("unroll") for (int n = 0; n < 4; ++n)                                           \
            _Pragma("unroll") for (int j = 0; j < 4; ++j) { EPILOG }

// bf16-out variant (z-sliced)
__global__ __launch_bounds__(256) void gemm_bt(const us* __restrict__ A_, const us* __restrict__ BT_,
                                               us* __restrict__ C, int K, int ldc, int nColReal,
                                               int colOff0, int colOffZ, long aStrideZ, long btStrideZ,
                                               int act) {
    const int z = blockIdx.z;
    const us* A = A_ + (size_t)z * aStrideZ;
    const us* BT = BT_ + (size_t)z * btStrideZ;
    const int colBase = colOff0 + z * colOffZ;
    GEMM_BODY(
        int cc = (int)bn * 128 + wc * 64 + n * 16 + r16;
        if (cc < nColReal) {
            long row = bm * 128 + wr * 64 + m * 16 + g4 * 4 + j;
            float v = acc[m][n][j];
            if (act) v = (v > 0.f) ? v : expm1f(v);
            C[row * (long)ldc + colBase + cc] = f2b(v);
        })
}

// f32-out variant (attention scalars sc; optional bias for dense out-init)
__global__ __launch_bounds__(256) void gemm_bt_f32(const us* __restrict__ A, const us* __restrict__ BT,
                                                   float* __restrict__ C, int K, int ldc, int nColReal,
                                                   const float* __restrict__ bias) {
    GEMM_BODY(
        int cc = (int)bn * 128 + wc * 64 + n * 16 + r16;
        if (cc < nColReal) {
            long row = bm * 128 + wr * 64 + m * 16 + g4 * 4 + j;
            float v = acc[m][n][j];
            if (bias) v += bias[cc];
            C[row * (long)ldc + cc] = v;
        })
}

// ---------------- small relation matmuls ----------------
__global__ __launch_bounds__(256) void rel0_kernel(const float* __restrict__ rel, const float* __restrict__ g0rk,
                                                   float* __restrict__ rel0b) {
    int idx = blockIdx.x * 256 + threadIdx.x;
    if (idx >= 500 * 150) return;
    int rI = idx / 150, u = idx % 150;
    float s = 0.f;
    for (int k = 0; k < 50; ++k) s += rel[rI * 50 + k] * g0rk[k * 150 + u];
    rel0b[idx] = s;
}

__global__ __launch_bounds__(256) void pr1_kernel(const float* __restrict__ rel0b, const float* __restrict__ g1k,
                                                  us* __restrict__ PR1b) {
    int idx = blockIdx.x * 256 + threadIdx.x;
    if (idx >= 500 * 2400) return;
    int rI = idx / 2400, jj = idx % 2400;
    int hd = jj / 300, u = jj % 300;
    float s = 0.f;
    for (int k = 0; k < 150; ++k)
        s += rel0b[rI * 150 + k] * g1k[((size_t)hd * 2550 + 1200 + k) * 300 + u];
    PR1b[idx] = f2b(s);
}

__global__ __launch_bounds__(256) void rel1_kernel(const float* __restrict__ rel0b, const float* __restrict__ g1rk,
                                                   float* __restrict__ out) {
    int idx = blockIdx.x * 256 + threadIdx.x;
    if (idx >= 500 * 300) return;
    int rI = idx / 300, u = idx % 300;
    float s = 0.f;
    for (int k = 0; k < 150; ++k) s += rel0b[rI * 150 + k] * g1rk[k * 300 + u];
    out[idx] = s;
}

// ---------------- layer-1 aggregation: 2 heads per launch, LDS-staged, race-free ----------------
__global__ __launch_bounds__(256) void agg1h2(int g, const int* __restrict__ rs, const int* __restrict__ se,
                                              const int* __restrict__ rIdx, const int* __restrict__ tIdx,
                                              const us* __restrict__ eAT, const float* __restrict__ sfac,
                                              const us* __restrict__ C1g2, const us* __restrict__ PR1b,
                                              float* __restrict__ outf) {
    __shared__ int sr[128], st[128];
    __shared__ float sa0[128], sa1[128];
    long n = blockIdx.x;
    int tid = threadIdx.x;
    int hd0 = 2 * g, hd1 = hd0 + 1;
    int d = tid, d2 = tid + 256;
    bool a2 = (d2 < 300);
    float sf0 = sfac[n * 8 + hd0], sf1 = sfac[n * 8 + hd1];
    const us* crow = C1g2 + (size_t)n * 1216;
    float acc00 = sf0 * b2f(crow[d]);
    float acc10 = sf1 * b2f(crow[304 + d]);
    float acc01 = a2 ? sf0 * b2f(crow[d2]) : 0.f;
    float acc11 = a2 ? sf1 * b2f(crow[304 + d2]) : 0.f;
    const us* ea0 = eAT + (size_t)hd0 * 400000;
    const us* ea1 = eAT + (size_t)hd1 * 400000;
    int p0 = rs[n], p1 = rs[n + 1];
    for (int c0 = p0; c0 < p1; c0 += 128) {
        int cnt = min(128, p1 - c0);
        __syncthreads();
        if (tid < cnt) {
            int e = se[c0 + tid];
            sr[tid] = rIdx[e];
            st[tid] = tIdx[e];
            sa0[tid] = b2f(ea0[c0 + tid]);
            sa1[tid] = b2f(ea1[c0 + tid]);
        }
        __syncthreads();
#pragma unroll 4
        for (int i = 0; i < cnt; ++i) {
            int r = sr[i], t = st[i];
            float a0 = sa0[i], a1 = sa1[i];
            const us* ct = C1g2 + (size_t)t * 1216;
            const us* pr = PR1b + (size_t)r * 2400;
            acc00 += a0 * (b2f(pr[hd0 * 300 + d]) + b2f(ct[608 + d]));
            acc10 += a1 * (b2f(pr[hd1 * 300 + d]) + b2f(ct[912 + d]));
            if (a2) {
                acc01 += a0 * (b2f(pr[hd0 * 300 + d2]) + b2f(ct[608 + d2]));
                acc11 += a1 * (b2f(pr[hd1 * 300 + d2]) + b2f(ct[912 + d2]));
            }
        }
    }
    float v00 = (acc00 > 0.f) ? acc00 : expm1f(acc00);
    float v10 = (acc10 > 0.f) ? acc10 : expm1f(acc10);
    outf[n * 300 + d] += v00 + v10;
    if (a2) {
        float v01 = (acc01 > 0.f) ? acc01 : expm1f(acc01);
        float v11 = (acc11 > 0.f) ? acc11 : expm1f(acc11);
        outf[n * 300 + d2] += v01 + v11;
    }
}

extern "C" void kernel_launch(void* const* d_in, const int* in_sizes, int n_in,
                              void* d_out, int out_size, void* d_ws, size_t ws_size,
                              hipStream_t stream) {
    const int* hIdx = (const int*)d_in[0];
    const int* rIdx = (const int*)d_in[1];
    const int* tIdx = (const int*)d_in[2];
    const float* ent  = (const float*)d_in[3];
    const float* rel  = (const float*)d_in[4];
    const float* g0k  = (const float*)d_in[5];
    const float* at0w = (const float*)d_in[6];
    const float* g0rk = (const float*)d_in[7];
    const float* g1k  = (const float*)d_in[8];
    const float* at1w = (const float*)d_in[9];
    const float* g1rk = (const float*)d_in[10];
    const float* dw   = (const float*)d_in[11];
    const float* db   = (const float*)d_in[12];
    float* outf = (float*)d_out;

    {
        const int exp_sz[13] = {400000, 400000, 400000, 2000000, 25000, 180000, 1200,
                                7500, 6120000, 2400, 45000, 15000, 300};
        bool ok = (n_in == 13);
        for (int i = 0; ok && i < 13; ++i) ok = (in_sizes[i] == exp_sz[i]);
        if (!ok) {
            sentinel<<<(out_size + 255) / 256, 256, 0, stream>>>(outf, out_size, 44.0f);
            return;
        }
    }

    char* p = (char*)d_ws;
    auto carve = [&](size_t bytes) -> char* {
        char* r = p;
        p += (bytes + 255) & ~(size_t)255;
        return r;
    };
    int* counts = (int*)carve(40000 * 4);
    int* cursor = (int*)carve(40000 * 4);
    int* rs     = (int*)carve(40001 * 4);
    int* se     = (int*)carve(400000 * 4);
    float* sc   = (float*)carve((size_t)40064 * 16 * 4);
    float* arS  = (float*)carve(500 * 8 * 4);
    us* eAT     = (us*)carve((size_t)8 * 400000 * 2);
    float* sfac = (float*)carve((size_t)40000 * 8 * 4);
    float* V0  = (float*)carve(50 * 24 * 4);
    float* Vr1 = (float*)carve(150 * 8 * 4);
    float* rel0b = (float*)carve(500 * 150 * 4);
    us* PR1b  = (us*)carve((size_t)500 * 2400 * 2);
    us* VT0   = (us*)carve((size_t)128 * 64 * 2);
    us* VT1   = (us*)carve((size_t)128 * 1216 * 2);
    us* dwT   = (us*)carve((size_t)384 * 64 * 2);
    us* B0T8  = (us*)carve((size_t)8 * 256 * 192 * 2);
    us* B1Th2 = (us*)carve((size_t)1280 * 1216 * 2);
    us* feat  = (us*)carve((size_t)40064 * 1216 * 2);
    // tail: A0 -> sS -> X0 -> sS -> C1g2 (sequentially dead)
    char* tail = p;
    us* A0    = (us*)tail;
    float* sS = (float*)tail;
    us* X0    = (us*)tail;
    us* C1g2  = (us*)tail;
    size_t tailNeed = (size_t)40064 * 1216 * 2;
    size_t totalNeed = (size_t)(tail - (char*)d_ws) + tailNeed;
    if (totalNeed > ws_size) {
        sentinel<<<(out_size + 255) / 256, 256, 0, stream>>>(outf, out_size, 42.0f);
        return;
    }

    hipMemsetAsync(counts, 0, 40000 * 4, stream);
    hipMemsetAsync(cursor, 0, 40000 * 4, stream);
    zero_featpad<<<(40064 * 16 + 255) / 256, 256, 0, stream>>>(feat);

    count_edges<<<1563, 256, 0, stream>>>(hIdx, counts);
    scan40k<<<1, 1024, 0, stream>>>(counts, rs);
    scatter_edges<<<1563, 256, 0, stream>>>(hIdx, rs, cursor, se);

    // ---- layer 0: attention scalars + dense out-init via MFMA (A0 alive in tail) ----
    pack_ent<<<(40064 * 64 + 255) / 256, 256, 0, stream>>>(ent, A0);
    build_VT0<<<(128 * 64 + 255) / 256, 256, 0, stream>>>(g0k, at0w, VT0);
    gemm_bt_f32<<<dim3(1, 313), 256, 0, stream>>>(A0, VT0, sc, 64, 16, 16, nullptr);
    build_dwT<<<(384 * 64 + 255) / 256, 256, 0, stream>>>(dw, dwT);
    gemm_bt_f32<<<dim3(3, 313), 256, 0, stream>>>(A0, dwT, outf, 64, 300, 300, db);
    build_V0<<<5, 256, 0, stream>>>(g0k, at0w, V0);
    scalar_proj<<<500, 256, 0, stream>>>(rel, 1, 50, 50, V0, 24, 16, 8, arS);
    edge_stats2<<<1250, 256, 0, stream>>>(rs, se, rIdx, tIdx, sc, arS, eAT, sfac, sS);  // A0 dead now

    zero_x0pad<<<(4 * 64 * 192 + 255) / 256, 256, 0, stream>>>(X0);  // after sS dead
    build_B0T8<<<(8 * 256 * 192 + 255) / 256, 256, 0, stream>>>(g0k, B0T8);
    for (int g = 0; g < 2; ++g) {
        agg0x4<<<40000, 256, 0, stream>>>(g, rs, se, rIdx, tIdx, eAT, sfac, ent, rel, X0);
        gemm_bt<<<dim3(2, 313, 4), 256, 0, stream>>>(X0, B0T8 + (size_t)g * 4 * 256 * 192, feat,
                                                     192, 1216, 150, g * 600, 150,
                                                     (long)40064 * 192, (long)256 * 192, 1);
    }

    // ---- layer 1 prep ----
    rel0_kernel<<<(500 * 150 + 255) / 256, 256, 0, stream>>>(rel, g0rk, rel0b);
    build_VT1<<<(128 * 1216 + 255) / 256, 256, 0, stream>>>(g1k, at1w, VT1);
    build_Vr1<<<5, 256, 0, stream>>>(g1k, at1w, Vr1);
    gemm_bt_f32<<<dim3(1, 313), 256, 0, stream>>>(feat, VT1, sc, 1216, 16, 16, nullptr);
    scalar_proj<<<500, 256, 0, stream>>>(rel0b, 1, 150, 150, Vr1, 8, 0, 8, arS);
    edge_stats2<<<1250, 256, 0, stream>>>(rs, se, rIdx, tIdx, sc, arS, eAT, sfac, sS);  // X0 dead now
    pr1_kernel<<<(500 * 2400 + 255) / 256, 256, 0, stream>>>(rel0b, g1k, PR1b);

    // ---- layer 1: head pairs ----
    for (int g = 0; g < 4; ++g) {
        build_B1Th2T<<<dim3(20, 19), 256, 0, stream>>>(g, g1k, B1Th2);
        gemm_bt<<<dim3(10, 313, 1), 256, 0, stream>>>(feat, B1Th2, C1g2,
                                                      1216, 1216, 1216, 0, 0, 0, 0, 0);
        agg1h2<<<40000, 256, 0, stream>>>(g, rs, se, rIdx, tIdx, eAT, sfac, C1g2, PR1b, outf);
    }

    rel1_kernel<<<(500 * 300 + 255) / 256, 256, 0, stream>>>(rel0b, g1rk, outf + (size_t)40000 * 300);
}